// Round 1
// 156.377 us; speedup vs baseline: 1.0123x; 1.0123x over previous
//
#include <hip/hip_runtime.h>
#include <hip/hip_bf16.h>

#define B_N 16384
#define TAU 0.25f
#define GS 68     // G leading dim (floats); 16B-aligned rows
#define YS 132    // Y leading dim (floats); EVEN -> 16B-aligned rows for f32x4 reads

typedef float f32x4 __attribute__((ext_vector_type(4)));
typedef short s16x8 __attribute__((ext_vector_type(8)));

__device__ __forceinline__ void gl_lds16(const void* g, void* l) {
    __builtin_amdgcn_global_load_lds(
        (const __attribute__((address_space(1))) void*)g,
        (__attribute__((address_space(3))) void*)l, 16, 0, 0);
}

__device__ __forceinline__ unsigned short bf16_bits(float v) {
    __hip_bfloat16 h = __float2bfloat16(v);
    return *reinterpret_cast<unsigned short*>(&h);
}

// ---------------------------------------------------------------------------
// Kernel 1 (merged): blocks 0..63 = per-cluster prep (512 thr = 8 waves);
// blocks 64..191 = convert. R10: prep restructured for latency:
//  - Gram split over two c-halves (all 8 waves busy)
//  - full L^{-1} assembled into G's strictly-upper triangle (diag = rinv tail)
//  - Z = Linv * D^T as a register-tiled fp32 GEMM over 512 threads with the
//    Qg/Bht stores fused in (replaces serial Phase E + Phase F).
// All arithmetic stays fp32; G/L/Lti bits identical to R9.
// ---------------------------------------------------------------------------
__global__ __launch_bounds__(512) void prep_convert(const float* __restrict__ x,
                                                    const float* __restrict__ D,
                                                    unsigned short* __restrict__ xh,
                                                    float* __restrict__ nrm,
                                                    float* __restrict__ Qg,
                                                    unsigned short* __restrict__ Bht,
                                                    float* __restrict__ out) {
    const int t = threadIdx.x;

    if (blockIdx.x >= 64) {
        // ---------------- convert path ----------------
        const int gid = (blockIdx.x - 64) * 512 + t;   // 0..65535 quarter-rows
        if (gid == 0) out[0] = 0.0f;
        const size_t base = (size_t)gid * 32;
        float s = 0.0f;
        #pragma unroll
        for (int c = 0; c < 8; ++c) {
            const f32x4 v = ((const f32x4*)(x + base))[c];
            s += v.x * v.x + v.y * v.y + v.z * v.z + v.w * v.w;
            ushort4 h;
            h.x = bf16_bits(v.x); h.y = bf16_bits(v.y);
            h.z = bf16_bits(v.z); h.w = bf16_bits(v.w);
            ((ushort4*)(xh + base))[c] = h;
        }
        s += __shfl_xor(s, 1, 64);
        s += __shfl_xor(s, 2, 64);
        if ((gid & 3) == 0) nrm[gid >> 2] = s;
        return;
    }

    // ---------------- prep path ----------------
    __shared__ float Y[64 * YS];                      // D^T (fp32), read by Phase Z
    __shared__ __align__(16) float G[64 * GS + 64];   // gram -> L (lower) + Linv (upper); tail = 1/L[i][i]
    __shared__ __align__(16) float Lti[8 * 8 * 8];    // 8x8 diag-block inverses
    const int n = blockIdx.x;
    const float* Dn = D + (size_t)n * 8192;

    // Phase A: Y[j][c] = Dn[c][j]
    for (int e4 = t; e4 < 2048; e4 += 512) {
        const int c = e4 >> 4, j4 = (e4 & 15) * 4;
        const f32x4 v = ((const f32x4*)Dn)[e4];
        Y[(j4 + 0) * YS + c] = v.x;
        Y[(j4 + 1) * YS + c] = v.y;
        Y[(j4 + 2) * YS + c] = v.z;
        Y[(j4 + 3) * YS + c] = v.w;
    }

    // Phase B: gram from global (L1-hot), split over two 64-row c-halves
    {
        const int h = t >> 8;                          // 0 or 1
        const int a0 = (t & 15) * 4, b0 = ((t >> 4) & 15) * 4;
        const int i0 = h * 64;
        float acc[4][4] = {};
        #pragma unroll 4
        for (int i = i0; i < i0 + 64; ++i) {
            const f32x4 av = *(const f32x4*)(Dn + i * 64 + a0);
            const f32x4 bv = *(const f32x4*)(Dn + i * 64 + b0);
            const float aa[4] = {av.x, av.y, av.z, av.w};
            const float bb[4] = {bv.x, bv.y, bv.z, bv.w};
            #pragma unroll
            for (int p = 0; p < 4; ++p)
                #pragma unroll
                for (int q = 0; q < 4; ++q) acc[p][q] = fmaf(aa[p], bb[q], acc[p][q]);
        }
        if (h == 0) {
            #pragma unroll
            for (int p = 0; p < 4; ++p)
                #pragma unroll
                for (int q = 0; q < 4; ++q) G[(a0 + p) * GS + b0 + q] = acc[p][q];
        }
        __syncthreads();
        if (h == 1) {
            #pragma unroll
            for (int p = 0; p < 4; ++p)
                #pragma unroll
                for (int q = 0; q < 4; ++q) G[(a0 + p) * GS + b0 + q] += acc[p][q];
        }
    }
    __syncthreads();

    // Phase C: blocked Cholesky, register-resident 8x8 panels
    for (int p8 = 0; p8 < 8; ++p8) {
        const int pb = p8 * 8;
        if (t < 64) {
            const int lane = t;
            const f32x4 v0 = *(const f32x4*)&G[lane * GS + pb];
            const f32x4 v1 = *(const f32x4*)&G[lane * GS + pb + 4];
            float g[8] = {v0.x, v0.y, v0.z, v0.w, v1.x, v1.y, v1.z, v1.w};
            #pragma unroll
            for (int kk = 0; kk < 8; ++kk) {
                const int k = pb + kk;
                const float dk = __shfl(g[kk], k, 64);
                const float rinv = 1.0f / sqrtf(dk);
                const float lik = g[kk] * rinv;
                g[kk] = lik;
                if (lane == 0) G[64 * GS + k] = rinv;
                #pragma unroll
                for (int jj = kk + 1; jj < 8; ++jj) {
                    const float ljk = __shfl(lik, pb + jj, 64);
                    g[jj] -= lik * ljk;
                }
            }
            *(f32x4*)&G[lane * GS + pb]     = (f32x4){g[0], g[1], g[2], g[3]};
            *(f32x4*)&G[lane * GS + pb + 4] = (f32x4){g[4], g[5], g[6], g[7]};
        }
        __syncthreads();
        const int base = pb + 8;
        if (base < 64) {
            for (int i = base + (t >> 5); i < 64; i += 16) {
                const f32x4 Li0 = *(const f32x4*)&G[i * GS + pb];
                const f32x4 Li1 = *(const f32x4*)&G[i * GS + pb + 4];
                for (int j = base + (t & 31); j < 64; j += 32) {
                    const f32x4 Lj0 = *(const f32x4*)&G[j * GS + pb];
                    const f32x4 Lj1 = *(const f32x4*)&G[j * GS + pb + 4];
                    float s = G[i * GS + j];
                    s -= Li0.x * Lj0.x + Li0.y * Lj0.y + Li0.z * Lj0.z + Li0.w * Lj0.w;
                    s -= Li1.x * Lj1.x + Li1.y * Lj1.y + Li1.z * Lj1.z + Li1.w * Lj1.w;
                    G[i * GS + j] = s;
                }
            }
        }
        __syncthreads();
    }

    // Phase D: invert 8x8 diagonal blocks
    if (t < 64) {
        const int bi = t >> 3, c = t & 7;
        const int base = bi * 8;
        float m[8];
        #pragma unroll
        for (int r = 0; r < 8; ++r) {
            float s = (r == c) ? 1.0f : 0.0f;
            #pragma unroll
            for (int k = 0; k < r; ++k)
                s -= G[(base + r) * GS + base + k] * m[k];
            m[r] = s * G[64 * GS + base + r];
        }
        #pragma unroll
        for (int r = 0; r < 8; ++r) Lti[(base + r) * 8 + c] = m[r];
    }
    __syncthreads();

    // Phase L: assemble full Linv = L^{-1} into G's strictly-upper triangle,
    // transposed: Linv[g][j] stored at G[j*GS+g] (g>j); diag = rinv tail.
    // thread t = (column j = t>>3, row-in-block r = t&7); wave w == j>>3, so
    // each wave owns 8 columns end-to-end (shfl exchanges w within the wave).
    {
        const int j = t >> 3, r = t & 7, jb = j >> 3;
        const float rinvj = G[64 * GS + j];
        for (int m8 = 0; m8 < 8; ++m8) {
            if (m8 >= jb) {
                const int g = m8 * 8 + r;
                float wv = (g == j) ? 1.0f : 0.0f;
                for (int mm = jb; mm < m8; ++mm) {
                    #pragma unroll
                    for (int kk = 0; kk < 8; ++kk) {
                        const int gp = mm * 8 + kk;
                        const float liv = (gp > j) ? G[j * GS + gp]
                                         : ((gp == j) ? rinvj : 0.0f);
                        wv -= G[g * GS + gp] * liv;
                    }
                }
                float z = 0.0f;
                #pragma unroll
                for (int rp = 0; rp < 8; ++rp) {
                    const float wrp = __shfl(wv, (t & 56) | rp, 64);
                    z = fmaf(Lti[g * 8 + rp], wrp, z);
                }
                if (g > j) G[j * GS + g] = z;
            }
            __syncthreads();
        }
    }

    // Phase Z: Z = Linv * Y (64x128, fp32), 4x4 per thread, epilogue fused.
    {
        const int j0 = (t >> 5) * 4, c0 = (t & 31) * 4;
        const f32x4 rv4 = *(const f32x4*)&G[64 * GS + j0];
        float acc[4][4] = {};   // [ej][ec]
        #pragma unroll 4
        for (int k = 0; k < j0; ++k) {
            const f32x4 lv = *(const f32x4*)&G[k * GS + j0];   // Linv[j0..j0+3][k]
            const f32x4 yv = *(const f32x4*)&Y[k * YS + c0];
            #pragma unroll
            for (int ej = 0; ej < 4; ++ej)
                #pragma unroll
                for (int ec = 0; ec < 4; ++ec)
                    acc[ej][ec] = fmaf(lv[ej], yv[ec], acc[ej][ec]);
        }
        #pragma unroll
        for (int kt = 0; kt < 4; ++kt) {           // masked diagonal tail
            const int k = j0 + kt;
            const f32x4 lq = *(const f32x4*)&G[k * GS + j0];
            const f32x4 yv = *(const f32x4*)&Y[k * YS + c0];
            #pragma unroll
            for (int ej = 0; ej < 4; ++ej) {
                const int jj = j0 + ej;
                const float lsel = (jj > k) ? lq[ej] : ((jj == k) ? rv4[ej] : 0.0f);
                #pragma unroll
                for (int ec = 0; ec < 4; ++ec)
                    acc[ej][ec] = fmaf(lsel, yv[ec], acc[ej][ec]);
            }
        }
        // epilogue: Qg[n][c][j] = Z[j][c] (f32x4), Bht[n][j][c] = bf16(Z[j][c])
        #pragma unroll
        for (int ec = 0; ec < 4; ++ec) {
            *(f32x4*)&Qg[(size_t)n * 8192 + (c0 + ec) * 64 + j0] =
                (f32x4){acc[0][ec], acc[1][ec], acc[2][ec], acc[3][ec]};
        }
        #pragma unroll
        for (int ej = 0; ej < 4; ++ej) {
            ushort4 h;
            h.x = bf16_bits(acc[ej][0]); h.y = bf16_bits(acc[ej][1]);
            h.z = bf16_bits(acc[ej][2]); h.w = bf16_bits(acc[ej][3]);
            *(ushort4*)&Bht[((size_t)n * 64 + j0 + ej) * 128 + c0] = h;
        }
    }
}

// ---------------------------------------------------------------------------
// Kernel 2: MFMA scores. Grid (128 m-tiles, 8 n-splits) = 1024 blocks.
// (byte-identical to R9)
// ---------------------------------------------------------------------------
__global__ __launch_bounds__(256) void gemm_scores(const unsigned short* __restrict__ xh,
                                                   const unsigned short* __restrict__ Bht,
                                                   float* __restrict__ S) {
    __shared__ unsigned short ldsA[128 * 128];   // 32 KB
    __shared__ unsigned short ldsB[64 * 128];    // 16 KB
    const int t = threadIdx.x, w = t >> 6, lane = t & 63;
    const int m0 = blockIdx.x * 128;
    const int n0 = blockIdx.y * 8;               // first cluster of this split
    const int lm = lane & 15, lg = lane >> 4;

    // ---- stage A (once) + B tile 0 ----
    {
        const int rl = lane >> 4, p = lane & 15;
        #pragma unroll
        for (int q = 0; q < 8; ++q) {
            const int row = w * 32 + q * 4 + rl;
            const int c = p ^ (row & 15);
            gl_lds16(xh + (size_t)(m0 + row) * 128 + c * 8,
                     &ldsA[(w * 32 + q * 4) * 128]);
        }
        #pragma unroll
        for (int q = 0; q < 4; ++q) {
            const int row = w * 16 + q * 4 + rl;
            const int c = p ^ (row & 15);
            gl_lds16(Bht + ((size_t)n0 * 64 + row) * 128 + c * 8,
                     &ldsB[(w * 16 + q * 4) * 128]);
        }
    }
    __syncthreads();   // A + B0 staged

    // ---- A-frags register-resident: rows w*32 .. w*32+31 ----
    s16x8 af[2][4];
    #pragma unroll
    for (int mt = 0; mt < 2; ++mt) {
        const int r = w * 32 + mt * 16 + lm;
        #pragma unroll
        for (int ks = 0; ks < 4; ++ks) {
            const int p = (ks * 4 + lg) ^ (r & 15);
            af[mt][ks] = *(const s16x8*)&ldsA[r * 128 + p * 8];
        }
    }

    #pragma unroll 1
    for (int it = 0; it < 8; ++it) {
        const int nc = n0 + it;

        // frag reads (all waves read the same 64 B-rows)
        s16x8 bf[4][4];
        #pragma unroll
        for (int nt = 0; nt < 4; ++nt) {
            const int r = nt * 16 + lm;
            #pragma unroll
            for (int ks = 0; ks < 4; ++ks) {
                const int p = (ks * 4 + lg) ^ (r & 15);
                bf[nt][ks] = *(const s16x8*)&ldsB[r * 128 + p * 8];
            }
        }
        __syncthreads();   // reads done -> safe to overwrite ldsB

        if (it < 7) {      // kick next cluster's B tile (drained at end barrier)
            const int rl = lane >> 4, p = lane & 15;
            #pragma unroll
            for (int q = 0; q < 4; ++q) {
                const int row = w * 16 + q * 4 + rl;
                const int c = p ^ (row & 15);
                gl_lds16(Bht + ((size_t)(nc + 1) * 64 + row) * 128 + c * 8,
                         &ldsB[(w * 16 + q * 4) * 128]);
            }
        }

        // MFMAs + epilogue (full cluster per wave, 32 m-rows)
        #pragma unroll
        for (int mt = 0; mt < 2; ++mt) {
            f32x4 acc[4];
            #pragma unroll
            for (int nt = 0; nt < 4; ++nt) acc[nt] = (f32x4){0.f, 0.f, 0.f, 0.f};
            #pragma unroll
            for (int ks = 0; ks < 4; ++ks)
                #pragma unroll
                for (int nt = 0; nt < 4; ++nt)
                    acc[nt] = __builtin_amdgcn_mfma_f32_16x16x32_bf16(
                        af[mt][ks], bf[nt][ks], acc[nt], 0, 0, 0);
            #pragma unroll
            for (int rg = 0; rg < 4; ++rg) {
                float p = 0.0f;
                #pragma unroll
                for (int nt = 0; nt < 4; ++nt) {
                    const float v = acc[nt][rg];
                    p += v * v;
                }
                p += __shfl_xor(p, 1, 64);
                p += __shfl_xor(p, 2, 64);
                p += __shfl_xor(p, 4, 64);
                p += __shfl_xor(p, 8, 64);
                if (lm == 0)
                    S[(size_t)nc * B_N + m0 + w * 32 + mt * 16 + lg * 4 + rg] = p;
            }
        }
        __syncthreads();   // drains the kick -> ldsB = next cluster
    }
}

// ---------------------------------------------------------------------------
// Kernel 3: argmax + loss + exact rescore. 512 blocks x 32 samples
// (byte-identical to R9)
// ---------------------------------------------------------------------------
__global__ __launch_bounds__(256) void argmax_rescore(const float* __restrict__ Sa,
                                                      const float* __restrict__ nrm,
                                                      const float* __restrict__ x,
                                                      const float* __restrict__ Qg,
                                                      float* __restrict__ out) {
    __shared__ float tile[32 * 65];   // [sample][n]
    __shared__ int sflags[32];
    __shared__ int scnt;
    __shared__ float ssum;
    __shared__ float scorr[4];
    const int t = threadIdx.x, w = t >> 6, lane = t & 63;
    const int b0 = blockIdx.x * 32;
    if (t == 0) scnt = 0;

    // coalesced load + transpose: Sa[n][b0 + c] -> tile[c][n]
    for (int e = t; e < 512; e += 256) {
        const int n = e >> 3, c4 = e & 7;
        const f32x4 v = *(const f32x4*)&Sa[(size_t)n * B_N + b0 + c4 * 4];
        tile[(c4 * 4 + 0) * 65 + n] = v.x;
        tile[(c4 * 4 + 1) * 65 + n] = v.y;
        tile[(c4 * 4 + 2) * 65 + n] = v.z;
        tile[(c4 * 4 + 3) * 65 + n] = v.w;
    }
    __syncthreads();

    // per-thread argmax (threads 0..31), flag near-ties, loss partial
    if (t < 32) {
        float v1 = -1e30f, v2 = -1e30f;
        int n1 = 0;
        for (int n = 0; n < 64; ++n) {
            const float v = tile[t * 65 + n];
            if (v > v1) { v2 = v1; v1 = v; n1 = n; }
            else v2 = fmaxf(v2, v);
        }
        out[1 + b0 + t] = (float)n1;
        if (v1 - v2 < TAU) { const int i = atomicAdd(&scnt, 1); sflags[i] = t; }
        float err = nrm[b0 + t] - v1;
        err += __shfl_xor(err, 1, 64);
        err += __shfl_xor(err, 2, 64);
        err += __shfl_xor(err, 4, 64);
        err += __shfl_xor(err, 8, 64);
        err += __shfl_xor(err, 16, 64);
        if (t == 0) ssum = err;
    }
    if (lane == 0) scorr[w] = 0.0f;
    __syncthreads();

    // cooperative exact rescore of flagged samples (S column from LDS)
    const int nf = scnt;
    float corr = 0.0f;
    for (int f = w; f < nf; f += 4) {
        const int s = sflags[f];
        const int b2 = b0 + s;
        const float v = tile[s * 65 + lane];
        float vm = v;
        for (int off = 32; off; off >>= 1) vm = fmaxf(vm, __shfl_xor(vm, off, 64));
        unsigned long long mask = __ballot((vm - v) < TAU);
        float best = -1e30f;
        int bn = 0;
        while (mask) {
            const int nn = (int)__builtin_ctzll(mask);
            mask &= mask - 1;
            const float* Qn = Qg + (size_t)nn * 8192;
            const float* xb = x + (size_t)b2 * 128;
            float d0 = 0.0f, d1 = 0.0f, d2 = 0.0f, d3 = 0.0f;
            #pragma unroll
            for (int i = 0; i < 128; i += 4) {
                d0 = fmaf(Qn[(i + 0) * 64 + lane], xb[i + 0], d0);
                d1 = fmaf(Qn[(i + 1) * 64 + lane], xb[i + 1], d1);
                d2 = fmaf(Qn[(i + 2) * 64 + lane], xb[i + 2], d2);
                d3 = fmaf(Qn[(i + 3) * 64 + lane], xb[i + 3], d3);
            }
            const float dot = (d0 + d1) + (d2 + d3);
            float sv = dot * dot;
            for (int off = 32; off; off >>= 1) sv += __shfl_xor(sv, off, 64);
            if (sv > best) { best = sv; bn = nn; }
        }
        if (lane == 0) {
            out[1 + b2] = (float)bn;
            corr += vm - best;   // replace approx top score with exact best
        }
    }
    if (lane == 0 && corr != 0.0f) scorr[w] += corr;
    __syncthreads();
    if (t == 0)
        atomicAdd(out, ssum + scorr[0] + scorr[1] + scorr[2] + scorr[3]);
}

// ---------------------------------------------------------------------------
extern "C" void kernel_launch(void* const* d_in, const int* in_sizes, int n_in,
                              void* d_out, int out_size, void* d_ws, size_t ws_size,
                              hipStream_t stream) {
    const float* x = (const float*)d_in[0];   // [16384, 128]
    const float* D = (const float*)d_in[1];   // [64, 128, 64]
    float* out = (float*)d_out;               // [1 + 16384]

    char* ws = (char*)d_ws;
    unsigned short* xh  = (unsigned short*)(ws);                 // 4 MB
    unsigned short* Bht = (unsigned short*)(ws + (4u << 20));    // 1 MB
    float* Qg           = (float*)(ws + (5u << 20));             // 2 MB
    float* Sa           = (float*)(ws + (7u << 20));             // 4 MB
    float* nrm          = (float*)(ws + (11u << 20));            // 64 KB

    prep_convert<<<192, 512, 0, stream>>>(x, D, xh, nrm, Qg, Bht, out);
    gemm_scores<<<dim3(128, 8), 256, 0, stream>>>(xh, Bht, Sa);
    argmax_rescore<<<512, 256, 0, stream>>>(Sa, nrm, x, Qg, out);
}

// Round 2
// 142.388 us; speedup vs baseline: 1.1118x; 1.0982x over previous
//
#include <hip/hip_runtime.h>
#include <hip/hip_bf16.h>

#define B_N 16384
#define TAU 0.25f
#define GS 68     // G leading dim (floats); 16B-aligned rows
#define YS 132    // Y leading dim (floats); EVEN -> 16B-aligned rows for f32x4 reads
#define DS 68     // D_lds leading dim (floats); 16B-aligned rows

typedef float f32x4 __attribute__((ext_vector_type(4)));
typedef short s16x8 __attribute__((ext_vector_type(8)));

__device__ __forceinline__ void gl_lds16(const void* g, void* l) {
    __builtin_amdgcn_global_load_lds(
        (const __attribute__((address_space(1))) void*)g,
        (__attribute__((address_space(3))) void*)l, 16, 0, 0);
}

__device__ __forceinline__ unsigned short bf16_bits(float v) {
    __hip_bfloat16 h = __float2bfloat16(v);
    return *reinterpret_cast<unsigned short*>(&h);
}

__device__ __forceinline__ float readlane_f(float v, int l) {
    return __int_as_float(__builtin_amdgcn_readlane(__float_as_int(v), l));
}

// ---------------------------------------------------------------------------
// Kernel 1 (merged): blocks 0..63 = per-cluster prep (512 thr = 8 waves);
// blocks 64..191 = convert. R11 surgical latency fixes (numerics-identical):
//  - D staged row-major in LDS; Gram (Phase B) reads LDS, not global (L1 BW)
//  - Phase C p8 loop fully unrolled; __shfl -> v_readlane (no ds_bpermute)
//  - Phase L inner blocks vectorized to f32x4 LDS reads
//  - Phase Z zigzag warp balance
// ---------------------------------------------------------------------------
__global__ __launch_bounds__(512) void prep_convert(const float* __restrict__ x,
                                                    const float* __restrict__ D,
                                                    unsigned short* __restrict__ xh,
                                                    float* __restrict__ nrm,
                                                    float* __restrict__ Qg,
                                                    unsigned short* __restrict__ Bht,
                                                    float* __restrict__ out) {
    const int t = threadIdx.x;

    if (blockIdx.x >= 64) {
        // ---------------- convert path ----------------
        const int gid = (blockIdx.x - 64) * 512 + t;   // 0..65535 quarter-rows
        if (gid == 0) out[0] = 0.0f;
        const size_t base = (size_t)gid * 32;
        float s = 0.0f;
        #pragma unroll
        for (int c = 0; c < 8; ++c) {
            const f32x4 v = ((const f32x4*)(x + base))[c];
            s += v.x * v.x + v.y * v.y + v.z * v.z + v.w * v.w;
            ushort4 h;
            h.x = bf16_bits(v.x); h.y = bf16_bits(v.y);
            h.z = bf16_bits(v.z); h.w = bf16_bits(v.w);
            ((ushort4*)(xh + base))[c] = h;
        }
        s += __shfl_xor(s, 1, 64);
        s += __shfl_xor(s, 2, 64);
        if ((gid & 3) == 0) nrm[gid >> 2] = s;
        return;
    }

    // ---------------- prep path ----------------
    __shared__ float Y[64 * YS];                      // D^T (fp32), read by Phase Z
    __shared__ __align__(16) float Dl[128 * DS];      // D row-major, read by Phase B
    __shared__ __align__(16) float G[64 * GS + 64];   // gram -> L (lower) + Linv (upper); tail = 1/L[i][i]
    __shared__ __align__(16) float Lti[8 * 8 * 8];    // 8x8 diag-block inverses
    const int n = blockIdx.x;
    const float* Dn = D + (size_t)n * 8192;

    // Phase A: Y[j][c] = Dn[c][j] (transposed) + Dl[c][j] (row-major)
    for (int e4 = t; e4 < 2048; e4 += 512) {
        const int c = e4 >> 4, j4 = (e4 & 15) * 4;
        const f32x4 v = ((const f32x4*)Dn)[e4];
        *(f32x4*)&Dl[c * DS + j4] = v;
        Y[(j4 + 0) * YS + c] = v.x;
        Y[(j4 + 1) * YS + c] = v.y;
        Y[(j4 + 2) * YS + c] = v.z;
        Y[(j4 + 3) * YS + c] = v.w;
    }
    __syncthreads();   // Dl ready for Phase B

    // Phase B: gram from LDS (broadcast-friendly), split over two c-halves
    {
        const int h = t >> 8;                          // 0 or 1
        const int a0 = (t & 15) * 4, b0 = ((t >> 4) & 15) * 4;
        const int i0 = h * 64;
        float acc[4][4] = {};
        #pragma unroll 4
        for (int i = i0; i < i0 + 64; ++i) {
            const f32x4 av = *(const f32x4*)&Dl[i * DS + a0];
            const f32x4 bv = *(const f32x4*)&Dl[i * DS + b0];
            const float aa[4] = {av.x, av.y, av.z, av.w};
            const float bb[4] = {bv.x, bv.y, bv.z, bv.w};
            #pragma unroll
            for (int p = 0; p < 4; ++p)
                #pragma unroll
                for (int q = 0; q < 4; ++q) acc[p][q] = fmaf(aa[p], bb[q], acc[p][q]);
        }
        if (h == 0) {
            #pragma unroll
            for (int p = 0; p < 4; ++p)
                #pragma unroll
                for (int q = 0; q < 4; ++q) G[(a0 + p) * GS + b0 + q] = acc[p][q];
        }
        __syncthreads();
        if (h == 1) {
            #pragma unroll
            for (int p = 0; p < 4; ++p)
                #pragma unroll
                for (int q = 0; q < 4; ++q) G[(a0 + p) * GS + b0 + q] += acc[p][q];
        }
    }
    __syncthreads();

    // Phase C: blocked Cholesky, register-resident 8x8 panels.
    // Fully unrolled -> readlane (no ds_bpermute) on the serial diag chain.
    #pragma unroll
    for (int p8 = 0; p8 < 8; ++p8) {
        const int pb = p8 * 8;
        if (t < 64) {
            const int lane = t;
            const f32x4 v0 = *(const f32x4*)&G[lane * GS + pb];
            const f32x4 v1 = *(const f32x4*)&G[lane * GS + pb + 4];
            float g[8] = {v0.x, v0.y, v0.z, v0.w, v1.x, v1.y, v1.z, v1.w};
            #pragma unroll
            for (int kk = 0; kk < 8; ++kk) {
                const int k = pb + kk;
                const float dk = readlane_f(g[kk], k);
                const float rinv = 1.0f / sqrtf(dk);
                const float lik = g[kk] * rinv;
                g[kk] = lik;
                if (lane == 0) G[64 * GS + k] = rinv;
                #pragma unroll
                for (int jj = kk + 1; jj < 8; ++jj) {
                    const float ljk = readlane_f(lik, pb + jj);
                    g[jj] -= lik * ljk;
                }
            }
            *(f32x4*)&G[lane * GS + pb]     = (f32x4){g[0], g[1], g[2], g[3]};
            *(f32x4*)&G[lane * GS + pb + 4] = (f32x4){g[4], g[5], g[6], g[7]};
        }
        __syncthreads();
        const int base = pb + 8;
        if (base < 64) {
            for (int i = base + (t >> 5); i < 64; i += 16) {
                const f32x4 Li0 = *(const f32x4*)&G[i * GS + pb];
                const f32x4 Li1 = *(const f32x4*)&G[i * GS + pb + 4];
                for (int j = base + (t & 31); j < 64; j += 32) {
                    const f32x4 Lj0 = *(const f32x4*)&G[j * GS + pb];
                    const f32x4 Lj1 = *(const f32x4*)&G[j * GS + pb + 4];
                    float s = G[i * GS + j];
                    s -= Li0.x * Lj0.x + Li0.y * Lj0.y + Li0.z * Lj0.z + Li0.w * Lj0.w;
                    s -= Li1.x * Lj1.x + Li1.y * Lj1.y + Li1.z * Lj1.z + Li1.w * Lj1.w;
                    G[i * GS + j] = s;
                }
            }
        }
        __syncthreads();
    }

    // Phase D: invert 8x8 diagonal blocks
    if (t < 64) {
        const int bi = t >> 3, c = t & 7;
        const int base = bi * 8;
        float m[8];
        #pragma unroll
        for (int r = 0; r < 8; ++r) {
            float s = (r == c) ? 1.0f : 0.0f;
            #pragma unroll
            for (int k = 0; k < r; ++k)
                s -= G[(base + r) * GS + base + k] * m[k];
            m[r] = s * G[64 * GS + base + r];
        }
        #pragma unroll
        for (int r = 0; r < 8; ++r) Lti[(base + r) * 8 + c] = m[r];
    }
    __syncthreads();

    // Phase L: assemble full Linv = L^{-1} into G's strictly-upper triangle,
    // transposed: Linv[g][j] stored at G[j*GS+g] (g>j); diag = rinv tail.
    // thread t = (column j = t>>3, row-in-block r = t&7); wave w == j>>3.
    // Inner past-blocks (mm > jb) are pure Linv reads -> f32x4 vectorized.
    {
        const int j = t >> 3, r = t & 7, jb = j >> 3;
        const float rinvj = G[64 * GS + j];
        for (int m8 = 0; m8 < 8; ++m8) {
            if (m8 >= jb) {
                const int g = m8 * 8 + r;
                float wv = (g == j) ? 1.0f : 0.0f;
                if (m8 > jb) {
                    // mm == jb: mixed L/diag/zero selection (scalar)
                    #pragma unroll
                    for (int kk = 0; kk < 8; ++kk) {
                        const int gp = jb * 8 + kk;
                        const float liv = (gp > j) ? G[j * GS + gp]
                                         : ((gp == j) ? rinvj : 0.0f);
                        wv -= G[g * GS + gp] * liv;
                    }
                    // jb < mm < m8: pure Linv values, vector loads
                    for (int mm = jb + 1; mm < m8; ++mm) {
                        const f32x4 Lg0 = *(const f32x4*)&G[g * GS + mm * 8];
                        const f32x4 Lg1 = *(const f32x4*)&G[g * GS + mm * 8 + 4];
                        const f32x4 Mv0 = *(const f32x4*)&G[j * GS + mm * 8];
                        const f32x4 Mv1 = *(const f32x4*)&G[j * GS + mm * 8 + 4];
                        wv = fmaf(-Lg0.x, Mv0.x, wv);
                        wv = fmaf(-Lg0.y, Mv0.y, wv);
                        wv = fmaf(-Lg0.z, Mv0.z, wv);
                        wv = fmaf(-Lg0.w, Mv0.w, wv);
                        wv = fmaf(-Lg1.x, Mv1.x, wv);
                        wv = fmaf(-Lg1.y, Mv1.y, wv);
                        wv = fmaf(-Lg1.z, Mv1.z, wv);
                        wv = fmaf(-Lg1.w, Mv1.w, wv);
                    }
                }
                float z = 0.0f;
                #pragma unroll
                for (int rp = 0; rp < 8; ++rp) {
                    const float wrp = __shfl(wv, (t & 56) | rp, 64);
                    z = fmaf(Lti[g * 8 + rp], wrp, z);
                }
                if (g > j) G[j * GS + g] = z;
            }
            __syncthreads();
        }
    }

    // Phase Z: Z = Linv * Y (64x128, fp32), 4x4 per thread, epilogue fused.
    // Zigzag jz remap: warp w handles column-blocks {w, 15-w} -> balanced.
    {
        const int jj = t >> 5;
        const int jz = (jj & 1) ? (15 - (jj >> 1)) : (jj >> 1);
        const int j0 = jz * 4, c0 = (t & 31) * 4;
        const f32x4 rv4 = *(const f32x4*)&G[64 * GS + j0];
        float acc[4][4] = {};   // [ej][ec]
        #pragma unroll 4
        for (int k = 0; k < j0; ++k) {
            const f32x4 lv = *(const f32x4*)&G[k * GS + j0];   // Linv[j0..j0+3][k]
            const f32x4 yv = *(const f32x4*)&Y[k * YS + c0];
            #pragma unroll
            for (int ej = 0; ej < 4; ++ej)
                #pragma unroll
                for (int ec = 0; ec < 4; ++ec)
                    acc[ej][ec] = fmaf(lv[ej], yv[ec], acc[ej][ec]);
        }
        #pragma unroll
        for (int kt = 0; kt < 4; ++kt) {           // masked diagonal tail
            const int k = j0 + kt;
            const f32x4 lq = *(const f32x4*)&G[k * GS + j0];
            const f32x4 yv = *(const f32x4*)&Y[k * YS + c0];
            #pragma unroll
            for (int ej = 0; ej < 4; ++ej) {
                const int jjj = j0 + ej;
                const float lsel = (jjj > k) ? lq[ej] : ((jjj == k) ? rv4[ej] : 0.0f);
                #pragma unroll
                for (int ec = 0; ec < 4; ++ec)
                    acc[ej][ec] = fmaf(lsel, yv[ec], acc[ej][ec]);
            }
        }
        // epilogue: Qg[n][c][j] = Z[j][c] (f32x4), Bht[n][j][c] = bf16(Z[j][c])
        #pragma unroll
        for (int ec = 0; ec < 4; ++ec) {
            *(f32x4*)&Qg[(size_t)n * 8192 + (c0 + ec) * 64 + j0] =
                (f32x4){acc[0][ec], acc[1][ec], acc[2][ec], acc[3][ec]};
        }
        #pragma unroll
        for (int ej = 0; ej < 4; ++ej) {
            ushort4 h;
            h.x = bf16_bits(acc[ej][0]); h.y = bf16_bits(acc[ej][1]);
            h.z = bf16_bits(acc[ej][2]); h.w = bf16_bits(acc[ej][3]);
            *(ushort4*)&Bht[((size_t)n * 64 + j0 + ej) * 128 + c0] = h;
        }
    }
}

// ---------------------------------------------------------------------------
// Kernel 2: MFMA scores. Grid (128 m-tiles, 8 n-splits) = 1024 blocks.
// (byte-identical to R9)
// ---------------------------------------------------------------------------
__global__ __launch_bounds__(256) void gemm_scores(const unsigned short* __restrict__ xh,
                                                   const unsigned short* __restrict__ Bht,
                                                   float* __restrict__ S) {
    __shared__ unsigned short ldsA[128 * 128];   // 32 KB
    __shared__ unsigned short ldsB[64 * 128];    // 16 KB
    const int t = threadIdx.x, w = t >> 6, lane = t & 63;
    const int m0 = blockIdx.x * 128;
    const int n0 = blockIdx.y * 8;               // first cluster of this split
    const int lm = lane & 15, lg = lane >> 4;

    // ---- stage A (once) + B tile 0 ----
    {
        const int rl = lane >> 4, p = lane & 15;
        #pragma unroll
        for (int q = 0; q < 8; ++q) {
            const int row = w * 32 + q * 4 + rl;
            const int c = p ^ (row & 15);
            gl_lds16(xh + (size_t)(m0 + row) * 128 + c * 8,
                     &ldsA[(w * 32 + q * 4) * 128]);
        }
        #pragma unroll
        for (int q = 0; q < 4; ++q) {
            const int row = w * 16 + q * 4 + rl;
            const int c = p ^ (row & 15);
            gl_lds16(Bht + ((size_t)n0 * 64 + row) * 128 + c * 8,
                     &ldsB[(w * 16 + q * 4) * 128]);
        }
    }
    __syncthreads();   // A + B0 staged

    // ---- A-frags register-resident: rows w*32 .. w*32+31 ----
    s16x8 af[2][4];
    #pragma unroll
    for (int mt = 0; mt < 2; ++mt) {
        const int r = w * 32 + mt * 16 + lm;
        #pragma unroll
        for (int ks = 0; ks < 4; ++ks) {
            const int p = (ks * 4 + lg) ^ (r & 15);
            af[mt][ks] = *(const s16x8*)&ldsA[r * 128 + p * 8];
        }
    }

    #pragma unroll 1
    for (int it = 0; it < 8; ++it) {
        const int nc = n0 + it;

        // frag reads (all waves read the same 64 B-rows)
        s16x8 bf[4][4];
        #pragma unroll
        for (int nt = 0; nt < 4; ++nt) {
            const int r = nt * 16 + lm;
            #pragma unroll
            for (int ks = 0; ks < 4; ++ks) {
                const int p = (ks * 4 + lg) ^ (r & 15);
                bf[nt][ks] = *(const s16x8*)&ldsB[r * 128 + p * 8];
            }
        }
        __syncthreads();   // reads done -> safe to overwrite ldsB

        if (it < 7) {      // kick next cluster's B tile (drained at end barrier)
            const int rl = lane >> 4, p = lane & 15;
            #pragma unroll
            for (int q = 0; q < 4; ++q) {
                const int row = w * 16 + q * 4 + rl;
                const int c = p ^ (row & 15);
                gl_lds16(Bht + ((size_t)(nc + 1) * 64 + row) * 128 + c * 8,
                         &ldsB[(w * 16 + q * 4) * 128]);
            }
        }

        // MFMAs + epilogue (full cluster per wave, 32 m-rows)
        #pragma unroll
        for (int mt = 0; mt < 2; ++mt) {
            f32x4 acc[4];
            #pragma unroll
            for (int nt = 0; nt < 4; ++nt) acc[nt] = (f32x4){0.f, 0.f, 0.f, 0.f};
            #pragma unroll
            for (int ks = 0; ks < 4; ++ks)
                #pragma unroll
                for (int nt = 0; nt < 4; ++nt)
                    acc[nt] = __builtin_amdgcn_mfma_f32_16x16x32_bf16(
                        af[mt][ks], bf[nt][ks], acc[nt], 0, 0, 0);
            #pragma unroll
            for (int rg = 0; rg < 4; ++rg) {
                float p = 0.0f;
                #pragma unroll
                for (int nt = 0; nt < 4; ++nt) {
                    const float v = acc[nt][rg];
                    p += v * v;
                }
                p += __shfl_xor(p, 1, 64);
                p += __shfl_xor(p, 2, 64);
                p += __shfl_xor(p, 4, 64);
                p += __shfl_xor(p, 8, 64);
                if (lm == 0)
                    S[(size_t)nc * B_N + m0 + w * 32 + mt * 16 + lg * 4 + rg] = p;
            }
        }
        __syncthreads();   // drains the kick -> ldsB = next cluster
    }
}

// ---------------------------------------------------------------------------
// Kernel 3: argmax + loss + exact rescore. 512 blocks x 32 samples
// (byte-identical to R9)
// ---------------------------------------------------------------------------
__global__ __launch_bounds__(256) void argmax_rescore(const float* __restrict__ Sa,
                                                      const float* __restrict__ nrm,
                                                      const float* __restrict__ x,
                                                      const float* __restrict__ Qg,
                                                      float* __restrict__ out) {
    __shared__ float tile[32 * 65];   // [sample][n]
    __shared__ int sflags[32];
    __shared__ int scnt;
    __shared__ float ssum;
    __shared__ float scorr[4];
    const int t = threadIdx.x, w = t >> 6, lane = t & 63;
    const int b0 = blockIdx.x * 32;
    if (t == 0) scnt = 0;

    // coalesced load + transpose: Sa[n][b0 + c] -> tile[c][n]
    for (int e = t; e < 512; e += 256) {
        const int n = e >> 3, c4 = e & 7;
        const f32x4 v = *(const f32x4*)&Sa[(size_t)n * B_N + b0 + c4 * 4];
        tile[(c4 * 4 + 0) * 65 + n] = v.x;
        tile[(c4 * 4 + 1) * 65 + n] = v.y;
        tile[(c4 * 4 + 2) * 65 + n] = v.z;
        tile[(c4 * 4 + 3) * 65 + n] = v.w;
    }
    __syncthreads();

    // per-thread argmax (threads 0..31), flag near-ties, loss partial
    if (t < 32) {
        float v1 = -1e30f, v2 = -1e30f;
        int n1 = 0;
        for (int n = 0; n < 64; ++n) {
            const float v = tile[t * 65 + n];
            if (v > v1) { v2 = v1; v1 = v; n1 = n; }
            else v2 = fmaxf(v2, v);
        }
        out[1 + b0 + t] = (float)n1;
        if (v1 - v2 < TAU) { const int i = atomicAdd(&scnt, 1); sflags[i] = t; }
        float err = nrm[b0 + t] - v1;
        err += __shfl_xor(err, 1, 64);
        err += __shfl_xor(err, 2, 64);
        err += __shfl_xor(err, 4, 64);
        err += __shfl_xor(err, 8, 64);
        err += __shfl_xor(err, 16, 64);
        if (t == 0) ssum = err;
    }
    if (lane == 0) scorr[w] = 0.0f;
    __syncthreads();

    // cooperative exact rescore of flagged samples (S column from LDS)
    const int nf = scnt;
    float corr = 0.0f;
    for (int f = w; f < nf; f += 4) {
        const int s = sflags[f];
        const int b2 = b0 + s;
        const float v = tile[s * 65 + lane];
        float vm = v;
        for (int off = 32; off; off >>= 1) vm = fmaxf(vm, __shfl_xor(vm, off, 64));
        unsigned long long mask = __ballot((vm - v) < TAU);
        float best = -1e30f;
        int bn = 0;
        while (mask) {
            const int nn = (int)__builtin_ctzll(mask);
            mask &= mask - 1;
            const float* Qn = Qg + (size_t)nn * 8192;
            const float* xb = x + (size_t)b2 * 128;
            float d0 = 0.0f, d1 = 0.0f, d2 = 0.0f, d3 = 0.0f;
            #pragma unroll
            for (int i = 0; i < 128; i += 4) {
                d0 = fmaf(Qn[(i + 0) * 64 + lane], xb[i + 0], d0);
                d1 = fmaf(Qn[(i + 1) * 64 + lane], xb[i + 1], d1);
                d2 = fmaf(Qn[(i + 2) * 64 + lane], xb[i + 2], d2);
                d3 = fmaf(Qn[(i + 3) * 64 + lane], xb[i + 3], d3);
            }
            const float dot = (d0 + d1) + (d2 + d3);
            float sv = dot * dot;
            for (int off = 32; off; off >>= 1) sv += __shfl_xor(sv, off, 64);
            if (sv > best) { best = sv; bn = nn; }
        }
        if (lane == 0) {
            out[1 + b2] = (float)bn;
            corr += vm - best;   // replace approx top score with exact best
        }
    }
    if (lane == 0 && corr != 0.0f) scorr[w] += corr;
    __syncthreads();
    if (t == 0)
        atomicAdd(out, ssum + scorr[0] + scorr[1] + scorr[2] + scorr[3]);
}

// ---------------------------------------------------------------------------
extern "C" void kernel_launch(void* const* d_in, const int* in_sizes, int n_in,
                              void* d_out, int out_size, void* d_ws, size_t ws_size,
                              hipStream_t stream) {
    const float* x = (const float*)d_in[0];   // [16384, 128]
    const float* D = (const float*)d_in[1];   // [64, 128, 64]
    float* out = (float*)d_out;               // [1 + 16384]

    char* ws = (char*)d_ws;
    unsigned short* xh  = (unsigned short*)(ws);                 // 4 MB
    unsigned short* Bht = (unsigned short*)(ws + (4u << 20));    // 1 MB
    float* Qg           = (float*)(ws + (5u << 20));             // 2 MB
    float* Sa           = (float*)(ws + (7u << 20));             // 4 MB
    float* nrm          = (float*)(ws + (11u << 20));            // 64 KB

    prep_convert<<<192, 512, 0, stream>>>(x, D, xh, nrm, Qg, Bht, out);
    gemm_scores<<<dim3(128, 8), 256, 0, stream>>>(xh, Bht, Sa);
    argmax_rescore<<<512, 256, 0, stream>>>(Sa, nrm, x, Qg, out);
}

// Round 3
// 138.177 us; speedup vs baseline: 1.1456x; 1.0305x over previous
//
#include <hip/hip_runtime.h>
#include <hip/hip_bf16.h>

#define B_N 16384
#define TAU 0.25f
#define GS 68     // G leading dim (floats); 16B-aligned rows
#define YS 132    // Y leading dim (floats); EVEN -> 16B-aligned rows for f32x4 reads
#define DS 68     // D_lds leading dim (floats); 16B-aligned rows

typedef float f32x4 __attribute__((ext_vector_type(4)));
typedef short s16x8 __attribute__((ext_vector_type(8)));

__device__ __forceinline__ void gl_lds16(const void* g, void* l) {
    __builtin_amdgcn_global_load_lds(
        (const __attribute__((address_space(1))) void*)g,
        (__attribute__((address_space(3))) void*)l, 16, 0, 0);
}

__device__ __forceinline__ unsigned short bf16_bits(float v) {
    __hip_bfloat16 h = __float2bfloat16(v);
    return *reinterpret_cast<unsigned short*>(&h);
}

__device__ __forceinline__ float readlane_f(float v, int l) {
    return __int_as_float(__builtin_amdgcn_readlane(__float_as_int(v), l));
}

// ---------------------------------------------------------------------------
// Kernel 1 (merged): blocks 0..63 = per-cluster prep (512 thr = 8 waves);
// blocks 64..191 = convert. (byte-identical to R11)
// ---------------------------------------------------------------------------
__global__ __launch_bounds__(512) void prep_convert(const float* __restrict__ x,
                                                    const float* __restrict__ D,
                                                    unsigned short* __restrict__ xh,
                                                    float* __restrict__ nrm,
                                                    float* __restrict__ Qg,
                                                    unsigned short* __restrict__ Bht,
                                                    float* __restrict__ out) {
    const int t = threadIdx.x;

    if (blockIdx.x >= 64) {
        // ---------------- convert path ----------------
        const int gid = (blockIdx.x - 64) * 512 + t;   // 0..65535 quarter-rows
        if (gid == 0) out[0] = 0.0f;
        const size_t base = (size_t)gid * 32;
        float s = 0.0f;
        #pragma unroll
        for (int c = 0; c < 8; ++c) {
            const f32x4 v = ((const f32x4*)(x + base))[c];
            s += v.x * v.x + v.y * v.y + v.z * v.z + v.w * v.w;
            ushort4 h;
            h.x = bf16_bits(v.x); h.y = bf16_bits(v.y);
            h.z = bf16_bits(v.z); h.w = bf16_bits(v.w);
            ((ushort4*)(xh + base))[c] = h;
        }
        s += __shfl_xor(s, 1, 64);
        s += __shfl_xor(s, 2, 64);
        if ((gid & 3) == 0) nrm[gid >> 2] = s;
        return;
    }

    // ---------------- prep path ----------------
    __shared__ float Y[64 * YS];                      // D^T (fp32), read by Phase Z
    __shared__ __align__(16) float Dl[128 * DS];      // D row-major, read by Phase B
    __shared__ __align__(16) float G[64 * GS + 64];   // gram -> L (lower) + Linv (upper); tail = 1/L[i][i]
    __shared__ __align__(16) float Lti[8 * 8 * 8];    // 8x8 diag-block inverses
    const int n = blockIdx.x;
    const float* Dn = D + (size_t)n * 8192;

    // Phase A: Y[j][c] = Dn[c][j] (transposed) + Dl[c][j] (row-major)
    for (int e4 = t; e4 < 2048; e4 += 512) {
        const int c = e4 >> 4, j4 = (e4 & 15) * 4;
        const f32x4 v = ((const f32x4*)Dn)[e4];
        *(f32x4*)&Dl[c * DS + j4] = v;
        Y[(j4 + 0) * YS + c] = v.x;
        Y[(j4 + 1) * YS + c] = v.y;
        Y[(j4 + 2) * YS + c] = v.z;
        Y[(j4 + 3) * YS + c] = v.w;
    }
    __syncthreads();   // Dl ready for Phase B

    // Phase B: gram from LDS (broadcast-friendly), split over two c-halves
    {
        const int h = t >> 8;                          // 0 or 1
        const int a0 = (t & 15) * 4, b0 = ((t >> 4) & 15) * 4;
        const int i0 = h * 64;
        float acc[4][4] = {};
        #pragma unroll 4
        for (int i = i0; i < i0 + 64; ++i) {
            const f32x4 av = *(const f32x4*)&Dl[i * DS + a0];
            const f32x4 bv = *(const f32x4*)&Dl[i * DS + b0];
            const float aa[4] = {av.x, av.y, av.z, av.w};
            const float bb[4] = {bv.x, bv.y, bv.z, bv.w};
            #pragma unroll
            for (int p = 0; p < 4; ++p)
                #pragma unroll
                for (int q = 0; q < 4; ++q) acc[p][q] = fmaf(aa[p], bb[q], acc[p][q]);
        }
        if (h == 0) {
            #pragma unroll
            for (int p = 0; p < 4; ++p)
                #pragma unroll
                for (int q = 0; q < 4; ++q) G[(a0 + p) * GS + b0 + q] = acc[p][q];
        }
        __syncthreads();
        if (h == 1) {
            #pragma unroll
            for (int p = 0; p < 4; ++p)
                #pragma unroll
                for (int q = 0; q < 4; ++q) G[(a0 + p) * GS + b0 + q] += acc[p][q];
        }
    }
    __syncthreads();

    // Phase C: blocked Cholesky, register-resident 8x8 panels.
    #pragma unroll
    for (int p8 = 0; p8 < 8; ++p8) {
        const int pb = p8 * 8;
        if (t < 64) {
            const int lane = t;
            const f32x4 v0 = *(const f32x4*)&G[lane * GS + pb];
            const f32x4 v1 = *(const f32x4*)&G[lane * GS + pb + 4];
            float g[8] = {v0.x, v0.y, v0.z, v0.w, v1.x, v1.y, v1.z, v1.w};
            #pragma unroll
            for (int kk = 0; kk < 8; ++kk) {
                const int k = pb + kk;
                const float dk = readlane_f(g[kk], k);
                const float rinv = 1.0f / sqrtf(dk);
                const float lik = g[kk] * rinv;
                g[kk] = lik;
                if (lane == 0) G[64 * GS + k] = rinv;
                #pragma unroll
                for (int jj = kk + 1; jj < 8; ++jj) {
                    const float ljk = readlane_f(lik, pb + jj);
                    g[jj] -= lik * ljk;
                }
            }
            *(f32x4*)&G[lane * GS + pb]     = (f32x4){g[0], g[1], g[2], g[3]};
            *(f32x4*)&G[lane * GS + pb + 4] = (f32x4){g[4], g[5], g[6], g[7]};
        }
        __syncthreads();
        const int base = pb + 8;
        if (base < 64) {
            for (int i = base + (t >> 5); i < 64; i += 16) {
                const f32x4 Li0 = *(const f32x4*)&G[i * GS + pb];
                const f32x4 Li1 = *(const f32x4*)&G[i * GS + pb + 4];
                for (int j = base + (t & 31); j < 64; j += 32) {
                    const f32x4 Lj0 = *(const f32x4*)&G[j * GS + pb];
                    const f32x4 Lj1 = *(const f32x4*)&G[j * GS + pb + 4];
                    float s = G[i * GS + j];
                    s -= Li0.x * Lj0.x + Li0.y * Lj0.y + Li0.z * Lj0.z + Li0.w * Lj0.w;
                    s -= Li1.x * Lj1.x + Li1.y * Lj1.y + Li1.z * Lj1.z + Li1.w * Lj1.w;
                    G[i * GS + j] = s;
                }
            }
        }
        __syncthreads();
    }

    // Phase D: invert 8x8 diagonal blocks
    if (t < 64) {
        const int bi = t >> 3, c = t & 7;
        const int base = bi * 8;
        float m[8];
        #pragma unroll
        for (int r = 0; r < 8; ++r) {
            float s = (r == c) ? 1.0f : 0.0f;
            #pragma unroll
            for (int k = 0; k < r; ++k)
                s -= G[(base + r) * GS + base + k] * m[k];
            m[r] = s * G[64 * GS + base + r];
        }
        #pragma unroll
        for (int r = 0; r < 8; ++r) Lti[(base + r) * 8 + c] = m[r];
    }
    __syncthreads();

    // Phase L: assemble full Linv into G's strictly-upper triangle (transposed)
    {
        const int j = t >> 3, r = t & 7, jb = j >> 3;
        const float rinvj = G[64 * GS + j];
        for (int m8 = 0; m8 < 8; ++m8) {
            if (m8 >= jb) {
                const int g = m8 * 8 + r;
                float wv = (g == j) ? 1.0f : 0.0f;
                if (m8 > jb) {
                    #pragma unroll
                    for (int kk = 0; kk < 8; ++kk) {
                        const int gp = jb * 8 + kk;
                        const float liv = (gp > j) ? G[j * GS + gp]
                                         : ((gp == j) ? rinvj : 0.0f);
                        wv -= G[g * GS + gp] * liv;
                    }
                    for (int mm = jb + 1; mm < m8; ++mm) {
                        const f32x4 Lg0 = *(const f32x4*)&G[g * GS + mm * 8];
                        const f32x4 Lg1 = *(const f32x4*)&G[g * GS + mm * 8 + 4];
                        const f32x4 Mv0 = *(const f32x4*)&G[j * GS + mm * 8];
                        const f32x4 Mv1 = *(const f32x4*)&G[j * GS + mm * 8 + 4];
                        wv = fmaf(-Lg0.x, Mv0.x, wv);
                        wv = fmaf(-Lg0.y, Mv0.y, wv);
                        wv = fmaf(-Lg0.z, Mv0.z, wv);
                        wv = fmaf(-Lg0.w, Mv0.w, wv);
                        wv = fmaf(-Lg1.x, Mv1.x, wv);
                        wv = fmaf(-Lg1.y, Mv1.y, wv);
                        wv = fmaf(-Lg1.z, Mv1.z, wv);
                        wv = fmaf(-Lg1.w, Mv1.w, wv);
                    }
                }
                float z = 0.0f;
                #pragma unroll
                for (int rp = 0; rp < 8; ++rp) {
                    const float wrp = __shfl(wv, (t & 56) | rp, 64);
                    z = fmaf(Lti[g * 8 + rp], wrp, z);
                }
                if (g > j) G[j * GS + g] = z;
            }
            __syncthreads();
        }
    }

    // Phase Z: Z = Linv * Y (64x128, fp32), 4x4 per thread, epilogue fused.
    {
        const int jj = t >> 5;
        const int jz = (jj & 1) ? (15 - (jj >> 1)) : (jj >> 1);
        const int j0 = jz * 4, c0 = (t & 31) * 4;
        const f32x4 rv4 = *(const f32x4*)&G[64 * GS + j0];
        float acc[4][4] = {};   // [ej][ec]
        #pragma unroll 4
        for (int k = 0; k < j0; ++k) {
            const f32x4 lv = *(const f32x4*)&G[k * GS + j0];
            const f32x4 yv = *(const f32x4*)&Y[k * YS + c0];
            #pragma unroll
            for (int ej = 0; ej < 4; ++ej)
                #pragma unroll
                for (int ec = 0; ec < 4; ++ec)
                    acc[ej][ec] = fmaf(lv[ej], yv[ec], acc[ej][ec]);
        }
        #pragma unroll
        for (int kt = 0; kt < 4; ++kt) {
            const int k = j0 + kt;
            const f32x4 lq = *(const f32x4*)&G[k * GS + j0];
            const f32x4 yv = *(const f32x4*)&Y[k * YS + c0];
            #pragma unroll
            for (int ej = 0; ej < 4; ++ej) {
                const int jjj = j0 + ej;
                const float lsel = (jjj > k) ? lq[ej] : ((jjj == k) ? rv4[ej] : 0.0f);
                #pragma unroll
                for (int ec = 0; ec < 4; ++ec)
                    acc[ej][ec] = fmaf(lsel, yv[ec], acc[ej][ec]);
            }
        }
        #pragma unroll
        for (int ec = 0; ec < 4; ++ec) {
            *(f32x4*)&Qg[(size_t)n * 8192 + (c0 + ec) * 64 + j0] =
                (f32x4){acc[0][ec], acc[1][ec], acc[2][ec], acc[3][ec]};
        }
        #pragma unroll
        for (int ej = 0; ej < 4; ++ej) {
            ushort4 h;
            h.x = bf16_bits(acc[ej][0]); h.y = bf16_bits(acc[ej][1]);
            h.z = bf16_bits(acc[ej][2]); h.w = bf16_bits(acc[ej][3]);
            *(ushort4*)&Bht[((size_t)n * 64 + j0 + ej) * 128 + c0] = h;
        }
    }
}

// ---------------------------------------------------------------------------
// Kernel 2 (R12 fused): MFMA scores + online argmax + loss + exact rescore.
// 256 blocks x 64 samples, all 64 clusters per block; scores stay in LDS.
// Operand-swapped MFMA (j on M-axis): j-reduction is in-register; cross-wave
// quarter-sums via tiny scPart buffer (double-buffered, wave0 assembles one
// cluster behind). One barrier per cluster; B double-buffered via gl_lds16.
// ---------------------------------------------------------------------------
__global__ __launch_bounds__(256) void gemm_argmax(const unsigned short* __restrict__ xh,
                                                   const unsigned short* __restrict__ Bht,
                                                   const float* __restrict__ nrm,
                                                   const float* __restrict__ x,
                                                   const float* __restrict__ Qg,
                                                   float* __restrict__ out) {
    __shared__ __align__(16) unsigned short ldsA[64 * 128];      // 16 KB (xh tile)
    __shared__ __align__(16) unsigned short ldsB[2][64 * 128];   // 32 KB (cluster dbuf)
    __shared__ float scL[64 * 65];                               // 16.25 KB scores
    __shared__ float scPart[2][16][80];                          // 10 KB partials
    __shared__ int sflags[64];
    __shared__ int scnt;
    __shared__ float ssum;
    __shared__ float scorr[4];
    const int t = threadIdx.x, w = t >> 6, lane = t & 63;
    const int m0 = blockIdx.x * 64;
    const int lm = lane & 15, lg = lane >> 4;
    if (t == 0) scnt = 0;
    if (t < 4) scorr[t] = 0.0f;

    // ---- stage A (xh, once) + B cluster 0 ----
    {
        const int rl = lane >> 4, p = lane & 15;
        #pragma unroll
        for (int q = 0; q < 4; ++q) {
            const int row = w * 16 + q * 4 + rl;
            const int c = p ^ (row & 15);
            gl_lds16(xh + (size_t)(m0 + row) * 128 + c * 8,
                     &ldsA[(w * 16 + q * 4) * 128]);
        }
        #pragma unroll
        for (int q = 0; q < 4; ++q) {
            const int row = w * 16 + q * 4 + rl;
            const int c = p ^ (row & 15);
            gl_lds16(Bht + (size_t)row * 128 + c * 8,
                     &ldsB[0][(w * 16 + q * 4) * 128]);
        }
    }
    __syncthreads();

    // ---- sample-frags register-resident (B-operand): 4 st x 4 ks ----
    s16x8 bf[4][4];
    #pragma unroll
    for (int st = 0; st < 4; ++st) {
        const int r = st * 16 + lm;
        #pragma unroll
        for (int ks = 0; ks < 4; ++ks) {
            const int p = (ks * 4 + lg) ^ (r & 15);
            bf[st][ks] = *(const s16x8*)&ldsA[r * 128 + p * 8];
        }
    }

    float v1 = -1e30f, v2 = -1e30f;   // online argmax state (wave 0, lane = sample)
    int n1 = 0;

    #pragma unroll 1
    for (int it = 0; it < 64; ++it) {
        const int cur = it & 1;

        // this wave's j-quarter frags for cluster `it` (A-operand)
        s16x8 af[4];
        {
            const int r = w * 16 + lm;
            #pragma unroll
            for (int ks = 0; ks < 4; ++ks) {
                const int p = (ks * 4 + lg) ^ (r & 15);
                af[ks] = *(const s16x8*)&ldsB[cur][r * 128 + p * 8];
            }
        }

        // kick next cluster into the other buffer (drained at end barrier)
        if (it < 63) {
            const int rl = lane >> 4, p = lane & 15;
            #pragma unroll
            for (int q = 0; q < 4; ++q) {
                const int row = w * 16 + q * 4 + rl;
                const int c = p ^ (row & 15);
                gl_lds16(Bht + ((size_t)(it + 1) * 64 + row) * 128 + c * 8,
                         &ldsB[cur ^ 1][(w * 16 + q * 4) * 128]);
            }
        }

        // MFMA: z[j][sample]; per lane acc regs = 4 j-rows of one sample
        #pragma unroll
        for (int st = 0; st < 4; ++st) {
            f32x4 acc = (f32x4){0.f, 0.f, 0.f, 0.f};
            #pragma unroll
            for (int ks = 0; ks < 4; ++ks)
                acc = __builtin_amdgcn_mfma_f32_16x16x32_bf16(af[ks], bf[st][ks], acc, 0, 0, 0);
            float q = acc[0] * acc[0];
            q = fmaf(acc[1], acc[1], q);
            q = fmaf(acc[2], acc[2], q);
            q = fmaf(acc[3], acc[3], q);
            scPart[cur][w * 4 + lg][st * 16 + lm] = q;   // quarter partial
        }

        // assembly for previous cluster (wave 0 only, pipelined one behind)
        if (it > 0 && w == 0) {
            const int pb = cur ^ 1;
            float s = scPart[pb][0][lane];
            #pragma unroll
            for (int idx = 1; idx < 16; ++idx) s += scPart[pb][idx][lane];
            scL[lane * 65 + (it - 1)] = s;
            if (s > v1) { v2 = v1; v1 = s; n1 = it - 1; } else v2 = fmaxf(v2, s);
        }
        __syncthreads();
    }

    // final assembly (cluster 63) + labels + flags + loss partial
    if (w == 0) {
        float s = scPart[1][0][lane];
        #pragma unroll
        for (int idx = 1; idx < 16; ++idx) s += scPart[1][idx][lane];
        scL[lane * 65 + 63] = s;
        if (s > v1) { v2 = v1; v1 = s; n1 = 63; } else v2 = fmaxf(v2, s);
        out[1 + m0 + lane] = (float)n1;
        if (v1 - v2 < TAU) { const int i = atomicAdd(&scnt, 1); sflags[i] = lane; }
        float err = nrm[m0 + lane] - v1;
        err += __shfl_xor(err, 1, 64);
        err += __shfl_xor(err, 2, 64);
        err += __shfl_xor(err, 4, 64);
        err += __shfl_xor(err, 8, 64);
        err += __shfl_xor(err, 16, 64);
        err += __shfl_xor(err, 32, 64);
        if (lane == 0) ssum = err;
    }
    __syncthreads();

    // cooperative exact rescore of flagged samples (S row from scL)
    const int nf = scnt;
    float corr = 0.0f;
    for (int f = w; f < nf; f += 4) {
        const int s = sflags[f];
        const int b2 = m0 + s;
        const float v = scL[s * 65 + lane];
        float vm = v;
        for (int off = 32; off; off >>= 1) vm = fmaxf(vm, __shfl_xor(vm, off, 64));
        unsigned long long mask = __ballot((vm - v) < TAU);
        float best = -1e30f;
        int bn = 0;
        while (mask) {
            const int nn = (int)__builtin_ctzll(mask);
            mask &= mask - 1;
            const float* Qn = Qg + (size_t)nn * 8192;
            const float* xb = x + (size_t)b2 * 128;
            float d0 = 0.0f, d1 = 0.0f, d2 = 0.0f, d3 = 0.0f;
            #pragma unroll
            for (int i = 0; i < 128; i += 4) {
                d0 = fmaf(Qn[(i + 0) * 64 + lane], xb[i + 0], d0);
                d1 = fmaf(Qn[(i + 1) * 64 + lane], xb[i + 1], d1);
                d2 = fmaf(Qn[(i + 2) * 64 + lane], xb[i + 2], d2);
                d3 = fmaf(Qn[(i + 3) * 64 + lane], xb[i + 3], d3);
            }
            const float dot = (d0 + d1) + (d2 + d3);
            float sv = dot * dot;
            for (int off = 32; off; off >>= 1) sv += __shfl_xor(sv, off, 64);
            if (sv > best) { best = sv; bn = nn; }
        }
        if (lane == 0) {
            out[1 + b2] = (float)bn;
            corr += vm - best;   // replace approx top score with exact best
        }
    }
    if (lane == 0 && corr != 0.0f) scorr[w] += corr;
    __syncthreads();
    if (t == 0)
        atomicAdd(out, ssum + scorr[0] + scorr[1] + scorr[2] + scorr[3]);
}

// ---------------------------------------------------------------------------
extern "C" void kernel_launch(void* const* d_in, const int* in_sizes, int n_in,
                              void* d_out, int out_size, void* d_ws, size_t ws_size,
                              hipStream_t stream) {
    const float* x = (const float*)d_in[0];   // [16384, 128]
    const float* D = (const float*)d_in[1];   // [64, 128, 64]
    float* out = (float*)d_out;               // [1 + 16384]

    char* ws = (char*)d_ws;
    unsigned short* xh  = (unsigned short*)(ws);                 // 4 MB
    unsigned short* Bht = (unsigned short*)(ws + (4u << 20));    // 1 MB
    float* Qg           = (float*)(ws + (5u << 20));             // 2 MB
    float* nrm          = (float*)(ws + (11u << 20));            // 64 KB

    prep_convert<<<192, 512, 0, stream>>>(x, D, xh, nrm, Qg, Bht, out);
    gemm_argmax<<<256, 256, 0, stream>>>(xh, Bht, nrm, x, Qg, out);
}